// Round 2
// baseline (437.156 us; speedup 1.0000x reference)
//
#include <hip/hip_runtime.h>

// Sampler: pooled = mean over stride-2 grid of b [8,128,256,256] f32,
// then relu(pooled@fc1^T)@fc2^T -> [8,128] f32 (1024 out elems).
// a / attn_w / attn_b are dead (reference DCEs attn).

#define B_DIM 8
#define C_DIM 128
#define H_DIM 256
#define W_DIM 256
#define HWSZ  (H_DIM * W_DIM)      // 65536
#define NPLANE (B_DIM * C_DIM)     // 1024
#define NBLK  (NPLANE * 2)         // 2 blocks per plane

// Kernel 1: per-half-plane reduction over even rows / even cols.
// 2048 blocks x 256 threads (4 waves) -> 8192 waves = 32/CU (full occupancy).
// Each wave reads one even row per iter as 64 coalesced float4 (1 KB = full
// row); per thread 16 loads split over 2 independent accumulators.
__global__ __launch_bounds__(256) void pool_kernel(const float* __restrict__ b,
                                                   float* __restrict__ partial) {
    const int bid   = blockIdx.x;             // 0..2047
    const int plane = bid >> 1;
    const int half  = bid & 1;                // which group of 64 even-rows
    const float* base = b + (size_t)plane * HWSZ;
    const int tid  = threadIdx.x;
    const int col4 = tid & 63;                // float4 index in row
    const int rq   = tid >> 6;                // wave 0..3

    float acc0 = 0.f, acc1 = 0.f;
    #pragma unroll
    for (int i = 0; i < 16; i += 2) {
        const int er0 = (half << 6) + rq + 4 * i;        // even-row idx
        const int er1 = (half << 6) + rq + 4 * (i + 1);
        float4 v0 = ((const float4*)(base + (size_t)(er0 << 1) * W_DIM))[col4];
        float4 v1 = ((const float4*)(base + (size_t)(er1 << 1) * W_DIM))[col4];
        acc0 += v0.x + v0.z;                  // even columns only
        acc1 += v1.x + v1.z;
    }
    float acc = acc0 + acc1;

    #pragma unroll
    for (int off = 32; off > 0; off >>= 1)
        acc += __shfl_down(acc, off, 64);

    __shared__ float ws[4];
    if ((tid & 63) == 0) ws[rq] = acc;
    __syncthreads();
    if (tid == 0) partial[bid] = ws[0] + ws[1] + ws[2] + ws[3];
}

// Kernel 2: sum the 2 partials/plane, scale, then the two tiny FCs in LDS.
__global__ __launch_bounds__(256) void fc_kernel(const float* __restrict__ partial,
                                                 const float* __restrict__ fc1_w,  // [32,128]
                                                 const float* __restrict__ fc2_w,  // [128,32]
                                                 float* __restrict__ out) {        // [8,128]
    __shared__ float s_pooled[NPLANE];            // 1024
    __shared__ float s_fc1[32 * 129];             // +1 pad: kills bank conflicts
    __shared__ float s_fc2[128 * 33];
    __shared__ float s_hidden[B_DIM * 32];        // 256

    const int tid = threadIdx.x;
    for (int i = tid; i < NPLANE; i += 256)
        s_pooled[i] = (partial[2 * i] + partial[2 * i + 1]) * (1.0f / 65536.0f);
    for (int i = tid; i < 4096; i += 256) {
        int j = i >> 7, c = i & 127;
        s_fc1[j * 129 + c] = fc1_w[i];
    }
    for (int i = tid; i < 4096; i += 256) {
        int o = i >> 5, j = i & 31;
        s_fc2[o * 33 + j] = fc2_w[i];
    }
    __syncthreads();

    // hidden[b][j]: 256 outputs, one per thread
    {
        const int bb = tid >> 5, j = tid & 31;
        const float* p = s_pooled + bb * C_DIM;
        const float* w = s_fc1 + j * 129;
        float h = 0.f;
        #pragma unroll
        for (int c = 0; c < C_DIM; ++c) h += p[c] * w[c];
        s_hidden[tid] = h > 0.f ? h : 0.f;
    }
    __syncthreads();

    // out[b][o]: 1024 outputs, 4 per thread
    for (int idx = tid; idx < 1024; idx += 256) {
        const int bb = idx >> 7, o = idx & 127;
        const float* h = s_hidden + bb * 32;
        const float* w = s_fc2 + o * 33;
        float a = 0.f;
        #pragma unroll
        for (int j = 0; j < 32; ++j) a += h[j] * w[j];
        out[idx] = a;
    }
}

extern "C" void kernel_launch(void* const* d_in, const int* in_sizes, int n_in,
                              void* d_out, int out_size, void* d_ws, size_t ws_size,
                              hipStream_t stream) {
    const float* b     = (const float*)d_in[1];
    const float* fc1_w = (const float*)d_in[4];
    const float* fc2_w = (const float*)d_in[5];
    float* out     = (float*)d_out;
    float* partial = (float*)d_ws;                // 2048 floats of scratch

    pool_kernel<<<NBLK, 256, 0, stream>>>(b, partial);
    fc_kernel<<<1, 256, 0, stream>>>(partial, fc1_w, fc2_w, out);
}